// Round 14
// baseline (130.752 us; speedup 1.0000x reference)
//
#include <hip/hip_runtime.h>

#define NB 32
#define LL 2048
#define CH 512
#define BQ 512
#define HH 1024

typedef __attribute__((ext_vector_type(8))) short bf16x8;
typedef __attribute__((ext_vector_type(16))) float f32x16;

__device__ __forceinline__ unsigned int cvt_pk_bf16(float a, float b) {
  unsigned int r;
  asm("v_cvt_pk_bf16_f32 %0, %1, %2" : "=v"(r) : "v"(a), "v"(b));
  return r;   // lo16 = bf16(a), hi16 = bf16(b)
}

__device__ __forceinline__ float fast_tanh(float x) {
  float e = __builtin_amdgcn_exp2f(x * 2.885390081777927f);
  return 1.0f - 2.0f * __builtin_amdgcn_rcpf(e + 1.0f);
}

// ================ fused small prep ================
// [0,256)   : pack Wc -> wcbp (B-frag order, 65536 uint4)
// [256,384) : res_qc = query@Wq^T + bc (32768)
// [384,400) : zero logit (65536 f32)
// 400       : zero out (16384 f32)
__global__ __launch_bounds__(256) void k_prep(const float* __restrict__ Wc,
                                              uint4* __restrict__ wcbp,
                                              const float* __restrict__ query,
                                              const float* __restrict__ Wq,
                                              const float* __restrict__ bc,
                                              float* __restrict__ resqc,
                                              float* __restrict__ logit,
                                              float* __restrict__ out) {
  int bid = blockIdx.x, t = threadIdx.x;
  if (bid < 256) {
    int gid = bid * 256 + t;   // 65536 = 32 cg * 32 ks * 64 lanes
    int lane = gid & 63, ks = (gid >> 6) & 31, cg = gid >> 11;
    int lo = lane & 31, hi = lane >> 5;
    const float4* s = (const float4*)(Wc + (size_t)(cg * 32 + lo) * CH + hi * 8 + ks * 16);
    float4 v0 = s[0], v1 = s[1];
    uint4 p;
    p.x = cvt_pk_bf16(v0.x, v0.y);
    p.y = cvt_pk_bf16(v0.z, v0.w);
    p.z = cvt_pk_bf16(v1.x, v1.y);
    p.w = cvt_pk_bf16(v1.z, v1.w);
    wcbp[gid] = p;
  } else if (bid < 384) {
    int gid = (bid - 256) * 256 + t;   // 32768
    int b = gid >> 10, h = gid & 1023;
    const float4* q4 = (const float4*)(query + (size_t)b * BQ);
    const float4* w4 = (const float4*)(Wq + (size_t)h * BQ);
    float acc = 0.f;
#pragma unroll 4
    for (int i = 0; i < BQ / 4; ++i) {
      float4 a = q4[i], w = w4[i];
      acc += a.x * w.x + a.y * w.y + a.z * w.z + a.w * w.w;
    }
    resqc[gid] = acc + bc[h];
  } else if (bid < 400) {
    float4* p = (float4*)logit + (bid - 384) * 1024 + t;
#pragma unroll
    for (int i = 0; i < 4; ++i) p[i * 256] = (float4){0, 0, 0, 0};
  } else {
    float4* p = (float4*)out + t;
#pragma unroll
    for (int i = 0; i < 16; ++i) p[i * 256] = (float4){0, 0, 0, 0};
  }
}

// ---------------- main: B-in-registers, A LDS double-buffered ----------------
// 512 blocks x 512 thr (8 waves). Block = 256-col group x 512-row range
// (8 tiles of 64 rows). Wave = 64r x 32c: B = 32 cols x K=512 held in 128 VGPRs
// (loaded ONCE; zero global B traffic in the K-loop). acc[2] = 32 AGPR.
// A tile staged to [64][520] bf16 LDS (measured 0-conflict), double-buffered
// (2 x 66.5 KB) with T14 split-stage: loads issued before each K-half, written
// after -> staging hides under MFMA. One barrier per tile.
__global__ __launch_bounds__(512, 2) void k_logits_r(const float* __restrict__ ctx,
                                                     const uint4* __restrict__ bpk,
                                                     const float* __restrict__ resqc,
                                                     const float* __restrict__ Wo,
                                                     float* __restrict__ logit) {
  __shared__ unsigned short A[2][64 * 520];   // 2 x 66560 B

  const int t = threadIdx.x;
  const int bid = blockIdx.x;
  // XCD swizzle (bijective, 512%8==0): 4 consecutive wid = 4 cgroups of the
  // same row-range -> same XCD -> shared ctx tile in XCD L2/L3.
  const int wid = (bid & 7) * 64 + (bid >> 3);
  const int cg = wid & 3, rr = wid >> 2;     // cg: 256-col group; rr: row-range
  const int b = rr >> 2;
  const int lbase = (rr & 3) * 512;          // L-start of this range within batch
  const int wv = t >> 6, lane = t & 63;
  const int lo = lane & 31, hi = lane >> 5;

  // ---- B into registers: this wave's 32 cols, full K (128 VGPR) ----
  const int cg32 = cg * 8 + wv;              // 32-col group index 0..31
  bf16x8 fbreg[32];
  {
    const uint4* bp = bpk + (size_t)cg32 * 2048 + lane;
#pragma unroll
    for (int ks = 0; ks < 32; ++ks) {
      uint4 u = bp[ks * 64];
      __builtin_memcpy(&fbreg[ks], &u, 16);
    }
  }
  const int c0 = cg32 * 32;
  const float q0 = resqc[b * HH + c0 + lo];
  const float w0 = Wo[c0 + lo];

  const float* actx = ctx + ((size_t)(b * LL + lbase)) * CH;

  // prologue: stage tile 0 into buf 0 (64x512 f32 -> bf16, 16 float4/thread)
  {
    const float4* src = (const float4*)actx;
#pragma unroll
    for (int i = 0; i < 16; ++i) {
      int f = i * 512 + t;
      int r = f >> 7, c4 = f & 127;
      float4 v = src[f];
      uint2 w;
      w.x = cvt_pk_bf16(v.x, v.y);
      w.y = cvt_pk_bf16(v.z, v.w);
      *(uint2*)(A[0] + r * 520 + c4 * 4) = w;
    }
  }
  __syncthreads();

  for (int tt = 0; tt < 8; ++tt) {
    const char* a0 = (const char*)(A[tt & 1]) + lo * 1040 + hi * 16;
    unsigned short* An = A[(tt + 1) & 1];
    const float4* srcn = (const float4*)(actx + (size_t)(tt + 1) * 64 * CH);

    f32x16 acc0 = {0,0,0,0,0,0,0,0,0,0,0,0,0,0,0,0};
    f32x16 acc1 = {0,0,0,0,0,0,0,0,0,0,0,0,0,0,0,0};

    float4 sv[8];
    if (tt < 7) {                    // issue next-tile half-1 loads (hide under K-half 1)
#pragma unroll
      for (int i = 0; i < 8; ++i) sv[i] = srcn[i * 512 + t];
    }
    // ---- K first half: ks 0..15; B from registers, A from LDS ----
#pragma unroll
    for (int ks = 0; ks < 16; ++ks) {
      bf16x8 fa0 = *(const bf16x8*)(a0 + ks * 32);
      bf16x8 fa1 = *(const bf16x8*)(a0 + 33280 + ks * 32);
      acc0 = __builtin_amdgcn_mfma_f32_32x32x16_bf16(fa0, fbreg[ks], acc0, 0, 0, 0);
      acc1 = __builtin_amdgcn_mfma_f32_32x32x16_bf16(fa1, fbreg[ks], acc1, 0, 0, 0);
    }
    if (tt < 7) {                    // write half-1, issue half-2 loads
#pragma unroll
      for (int i = 0; i < 8; ++i) {
        int f = i * 512 + t;
        int r = f >> 7, c4 = f & 127;
        uint2 w;
        w.x = cvt_pk_bf16(sv[i].x, sv[i].y);
        w.y = cvt_pk_bf16(sv[i].z, sv[i].w);
        *(uint2*)(An + r * 520 + c4 * 4) = w;
      }
#pragma unroll
      for (int i = 0; i < 8; ++i) sv[i] = srcn[(8 + i) * 512 + t];
    }
    // ---- K second half: ks 16..31 ----
#pragma unroll
    for (int ks = 16; ks < 32; ++ks) {
      bf16x8 fa0 = *(const bf16x8*)(a0 + ks * 32);
      bf16x8 fa1 = *(const bf16x8*)(a0 + 33280 + ks * 32);
      acc0 = __builtin_amdgcn_mfma_f32_32x32x16_bf16(fa0, fbreg[ks], acc0, 0, 0, 0);
      acc1 = __builtin_amdgcn_mfma_f32_32x32x16_bf16(fa1, fbreg[ks], acc1, 0, 0, 0);
    }
    if (tt < 7) {                    // write half-2
#pragma unroll
      for (int i = 0; i < 8; ++i) {
        int f = (8 + i) * 512 + t;
        int r = f >> 7, c4 = f & 127;
        uint2 w;
        w.x = cvt_pk_bf16(sv[i].x, sv[i].y);
        w.y = cvt_pk_bf16(sv[i].z, sv[i].w);
        *(uint2*)(An + r * 520 + c4 * 4) = w;
      }
    }

    // epilogue: tanh + Wo col-sum -> transpose-reduce -> global atomics
    float v[32];
#pragma unroll
    for (int r = 0; r < 16; ++r) {
      v[r]      = w0 * fast_tanh(acc0[r] + q0);
      v[16 + r] = w0 * fast_tanh(acc1[r] + q0);
    }
#pragma unroll
    for (int sdist = 16; sdist >= 1; sdist >>= 1) {
#pragma unroll
      for (int i = 0; i < sdist; ++i) {
        float a = v[i], c = v[i + sdist];
        float keep = (lo & sdist) ? c : a;
        float send = (lo & sdist) ? a : c;
        v[i] = keep + __shfl_xor(send, sdist, 64);
      }
    }
    int rm = lo & 15;
    int row_local = (lo >> 4) * 32 + (rm & 3) + 8 * (rm >> 2) + 4 * hi;  // C/D row map
    atomicAdd(&logit[(size_t)b * LL + lbase + tt * 64 + row_local], v[0]);

    __syncthreads();                 // buf swap: next tile reads An
  }
}

// ---------------- weights: mask*exp(logit+bo), normalize over L ----------------
__global__ __launch_bounds__(256) void k_weights(const float* __restrict__ mask,
                                                 const float* __restrict__ bo,
                                                 const float* __restrict__ logit,
                                                 float* __restrict__ wout) {
  __shared__ float red[4];
  int b = blockIdx.x, t = threadIdx.x;
  float bov = bo[0];
  float w[8];
  float s = 0.f;
#pragma unroll
  for (int i = 0; i < 8; ++i) {
    int l = t + 256 * i;
    float e = mask[b * LL + l] * __expf(logit[b * LL + l] + bov);
    w[i] = e; s += e;
  }
#pragma unroll
  for (int m = 32; m >= 1; m >>= 1) s += __shfl_xor(s, m, 64);
  int wave = t >> 6, lane = t & 63;
  if (lane == 0) red[wave] = s;
  __syncthreads();
  float inv = 1.0f / (red[0] + red[1] + red[2] + red[3] + 1e-5f);
#pragma unroll
  for (int i = 0; i < 8; ++i) wout[b * LL + t + 256 * i] = w[i] * inv;
}

// ---------------- output[b][c] = sum_l weights[b][l] * ctx[b][l][c] (ctx in L3) ----
__global__ __launch_bounds__(256) void k_output_f32(const float* __restrict__ ctx,
                                                    const float* __restrict__ weights,
                                                    float* __restrict__ out) {
  __shared__ float wl[128];
  int bid = blockIdx.x;            // 512 = 32 b * 16 chunks
  int b = bid >> 4, chunk = bid & 15;
  int t = threadIdx.x;
  int l0 = chunk * 128;
  if (t < 128) wl[t] = weights[b * LL + l0 + t];
  __syncthreads();
  const float2* c2 = (const float2*)(ctx + ((size_t)(b * LL + l0)) * CH) + t;
  float ax = 0.f, ay = 0.f;
#pragma unroll 4
  for (int l = 0; l < 128; ++l) {
    float wv = wl[l];
    float2 v = c2[(size_t)l * (CH / 2)];
    ax += wv * v.x; ay += wv * v.y;
  }
  atomicAdd(&out[b * CH + 2 * t], ax);
  atomicAdd(&out[b * CH + 2 * t + 1], ay);
}

extern "C" void kernel_launch(void* const* d_in, const int* in_sizes, int n_in,
                              void* d_out, int out_size, void* d_ws, size_t ws_size,
                              hipStream_t stream) {
  const float* query = (const float*)d_in[0];
  const float* ctx   = (const float*)d_in[1];
  const float* mask  = (const float*)d_in[2];
  const float* Wq    = (const float*)d_in[3];
  const float* Wc    = (const float*)d_in[4];
  const float* bc    = (const float*)d_in[5];
  const float* Wo    = (const float*)d_in[6];
  const float* bo    = (const float*)d_in[7];
  float* out = (float*)d_out;

  uint4* wcbp  = (uint4*)d_ws;                                    // 1 MB packed bf16 Wc
  float* resqc = (float*)((char*)d_ws + (1 << 20));               // 128 KB
  float* logit = (float*)((char*)d_ws + (1 << 20) + (1 << 17));   // 256 KB
  float* wout = out + NB * CH;                                    // final weights slot

  k_prep<<<401, 256, 0, stream>>>(Wc, wcbp, query, Wq, bc, resqc, logit, out);
  k_logits_r<<<512, 512, 0, stream>>>(ctx, wcbp, resqc, Wo, logit);
  k_weights<<<32, 256, 0, stream>>>(mask, bo, logit, wout);
  k_output_f32<<<512, 256, 0, stream>>>(ctx, wout, out);
}

// Round 15
// 130.530 us; speedup vs baseline: 1.0017x; 1.0017x over previous
//
#include <hip/hip_runtime.h>

#define NB 32
#define LL 2048
#define CH 512
#define BQ 512
#define HH 1024

typedef __attribute__((ext_vector_type(8))) short bf16x8;
typedef __attribute__((ext_vector_type(16))) float f32x16;

__device__ __forceinline__ unsigned int cvt_pk_bf16(float a, float b) {
  unsigned int r;
  asm("v_cvt_pk_bf16_f32 %0, %1, %2" : "=v"(r) : "v"(a), "v"(b));
  return r;   // lo16 = bf16(a), hi16 = bf16(b)
}

__device__ __forceinline__ float fast_tanh(float x) {
  float e = __builtin_amdgcn_exp2f(x * 2.885390081777927f);
  return 1.0f - 2.0f * __builtin_amdgcn_rcpf(e + 1.0f);
}

__device__ __forceinline__ void glds16(const void* g, void* l) {
  __builtin_amdgcn_global_load_lds((const __attribute__((address_space(1))) void*)g,
                                   (__attribute__((address_space(3))) void*)l, 16, 0, 0);
}

// ================ fused small prep ================
// [0,256)   : pack Wc -> wcbp (B-frag order, 65536 uint4)
// [256,384) : res_qc = query@Wq^T + bc (32768)
// [384,400) : zero logit (65536 f32)
// 400       : zero out (16384 f32)
__global__ __launch_bounds__(256) void k_prep(const float* __restrict__ Wc,
                                              uint4* __restrict__ wcbp,
                                              const float* __restrict__ query,
                                              const float* __restrict__ Wq,
                                              const float* __restrict__ bc,
                                              float* __restrict__ resqc,
                                              float* __restrict__ logit,
                                              float* __restrict__ out) {
  int bid = blockIdx.x, t = threadIdx.x;
  if (bid < 256) {
    int gid = bid * 256 + t;   // 65536 = 32 cg * 32 ks * 64 lanes
    int lane = gid & 63, ks = (gid >> 6) & 31, cg = gid >> 11;
    int lo = lane & 31, hi = lane >> 5;
    const float4* s = (const float4*)(Wc + (size_t)(cg * 32 + lo) * CH + hi * 8 + ks * 16);
    float4 v0 = s[0], v1 = s[1];
    uint4 p;
    p.x = cvt_pk_bf16(v0.x, v0.y);
    p.y = cvt_pk_bf16(v0.z, v0.w);
    p.z = cvt_pk_bf16(v1.x, v1.y);
    p.w = cvt_pk_bf16(v1.z, v1.w);
    wcbp[gid] = p;
  } else if (bid < 384) {
    int gid = (bid - 256) * 256 + t;   // 32768
    int b = gid >> 10, h = gid & 1023;
    const float4* q4 = (const float4*)(query + (size_t)b * BQ);
    const float4* w4 = (const float4*)(Wq + (size_t)h * BQ);
    float acc = 0.f;
#pragma unroll 4
    for (int i = 0; i < BQ / 4; ++i) {
      float4 a = q4[i], w = w4[i];
      acc += a.x * w.x + a.y * w.y + a.z * w.z + a.w * w.w;
    }
    resqc[gid] = acc + bc[h];
  } else if (bid < 400) {
    float4* p = (float4*)logit + (bid - 384) * 1024 + t;
#pragma unroll
    for (int i = 0; i < 4; ++i) p[i * 256] = (float4){0, 0, 0, 0};
  } else {
    float4* p = (float4*)out + t;
#pragma unroll
    for (int i = 0; i < 16; ++i) p[i * 256] = (float4){0, 0, 0, 0};
  }
}

// ---------------- main: 256x256 tile, BK=64, counted-vmcnt pipeline ----------------
// 1024 blocks x 512 thr (8 waves, 2M x 4N). Wave = 128r x 64c, acc[4][2]=128.
// A: ctx f32 -> reg -> cvt_pk -> LDS chunk (mt,c8,r5) @ (mt*8+c8)*512+16*(r5^c8)
//    (derived conflict-free on BOTH write [8 thr = 8x16B tiling all 32 banks]
//     and read [32 lanes = contiguous permuted 512B]).
// B: global_load_lds from packed wcbp (linear lane x 16B dest = read layout).
// Raw s_barrier with counted vmcnt: A(kt+2) loads stay in flight across it.
__global__ __launch_bounds__(512, 2) void k_logits_t(const float* __restrict__ ctx,
                                                     const uint4* __restrict__ bpk,
                                                     const float* __restrict__ resqc,
                                                     const float* __restrict__ Wo,
                                                     float* __restrict__ logit) {
  __shared__ char lds[131072];   // A: p*32768; B: 65536 + p*32768

  const int t = threadIdx.x;
  const int bid = blockIdx.x;
  const int g = (bid & 7) * 128 + (bid >> 3);   // XCD-bijective
  const int mtile = g >> 2, ntile = g & 3;      // 256 mtiles x 4 ntiles
  const int wv = t >> 6, lane = t & 63;
  const int wm = wv >> 2, wn = wv & 3;
  const int lo = lane & 31, hi = lane >> 5;
  const int b = mtile >> 3;

  // epilogue operands (loaded first; drained by later waits)
  const int c0 = ntile * 256 + wn * 64;
  const float q0 = resqc[b * HH + c0 + lo], q1 = resqc[b * HH + c0 + 32 + lo];
  const float w0 = Wo[c0 + lo],             w1 = Wo[c0 + 32 + lo];

  const float* actx = ctx + (size_t)mtile * 256 * CH;

  // A staging maps: thread t, chunk w: f = w*512+t; row=f>>3, c8=f&7
  int soff[4], sdst[4];
#pragma unroll
  for (int w = 0; w < 4; ++w) {
    int f = w * 512 + t;
    int row = f >> 3, c8 = f & 7;
    soff[w] = row * CH + c8 * 8;                               // f32 offset (+kt*64)
    sdst[w] = ((row >> 5) * 8 + c8) * 512 + 16 * ((row & 31) ^ c8);
  }
  // A frag read offsets per ks (c8 = ks*2+hi); + mt*4096
  int aro[4];
#pragma unroll
  for (int ks = 0; ks < 4; ++ks) {
    int c8 = ks * 2 + hi;
    aro[ks] = c8 * 512 + 16 * (lo ^ c8);
  }
  // B glds source base for this wave (stages cg = wv)
  const uint4* bsrc0 = bpk + ((size_t)(ntile * 8 + wv) * 32) * 64 + lane;

  float4 av[8];

#define LOADA(kt)                                                              \
  {                                                                            \
    _Pragma("unroll") for (int w = 0; w < 4; ++w) {                            \
      const float4* s = (const float4*)(actx + (size_t)soff[w] + (kt) * 64);   \
      av[2 * w] = s[0]; av[2 * w + 1] = s[1];                                  \
    }                                                                          \
  }
#define WRITEA(p)                                                              \
  {                                                                            \
    _Pragma("unroll") for (int w = 0; w < 4; ++w) {                            \
      uint4 pk;                                                                \
      pk.x = cvt_pk_bf16(av[2 * w].x, av[2 * w].y);                            \
      pk.y = cvt_pk_bf16(av[2 * w].z, av[2 * w].w);                            \
      pk.z = cvt_pk_bf16(av[2 * w + 1].x, av[2 * w + 1].y);                    \
      pk.w = cvt_pk_bf16(av[2 * w + 1].z, av[2 * w + 1].w);                    \
      *(uint4*)(lds + (p) * 32768 + sdst[w]) = pk;                             \
    }                                                                          \
  }
#define GLDSB(kt, p)                                                           \
  {                                                                            \
    _Pragma("unroll") for (int j = 0; j < 4; ++j)                              \
      glds16(bsrc0 + ((size_t)(kt) * 4 + j) * 64,                              \
             lds + 65536 + (p) * 32768 + (wv * 4 + j) * 1024);                 \
  }
#define COMPUTE(p, KS0, KS1)                                                   \
  {                                                                            \
    _Pragma("unroll") for (int ks = (KS0); ks <= (KS1); ++ks) {                \
      bf16x8 fb0 = *(const bf16x8*)(lds + 65536 + (p) * 32768 +                \
                                    ((wn * 2 + 0) * 4 + ks) * 1024 + lane * 16); \
      bf16x8 fb1 = *(const bf16x8*)(lds + 65536 + (p) * 32768 +                \
                                    ((wn * 2 + 1) * 4 + ks) * 1024 + lane * 16); \
      _Pragma("unroll") for (int m = 0; m < 4; ++m) {                          \
        bf16x8 fa = *(const bf16x8*)(lds + (p) * 32768 + (wm * 4 + m) * 4096 + \
                                     aro[ks]);                                 \
        acc[m][0] = __builtin_amdgcn_mfma_f32_32x32x16_bf16(fa, fb0, acc[m][0], 0, 0, 0); \
        acc[m][1] = __builtin_amdgcn_mfma_f32_32x32x16_bf16(fa, fb1, acc[m][1], 0, 0, 0); \
      }                                                                        \
    }                                                                          \
  }

  f32x16 acc[4][2];
#pragma unroll
  for (int m = 0; m < 4; ++m)
#pragma unroll
    for (int n = 0; n < 2; ++n) acc[m][n] = (f32x16){0,0,0,0,0,0,0,0,0,0,0,0,0,0,0,0};

  // ---- prologue ----
  LOADA(0);                 // 8 vm
  GLDSB(0, 0);              // 4 vm
  WRITEA(0);                // compiler waits vmcnt(4): av0 ready, B0 in flight
  LOADA(1);                 // 8 vm
  asm volatile("s_waitcnt vmcnt(8) lgkmcnt(0)" ::: "memory");  // B0 done; A1 flying
  __builtin_amdgcn_sched_barrier(0);
  __builtin_amdgcn_s_barrier();
  __builtin_amdgcn_sched_barrier(0);

  // ---- main loop: 8 K-steps ----
#pragma unroll
  for (int kt = 0; kt < 8; ++kt) {
    const int p = kt & 1, pn = p ^ 1;
    if (kt < 7) GLDSB(kt + 1, pn);            // B(kt+1) -> other buf (reads of it done)
    __builtin_amdgcn_sched_barrier(0);
    __builtin_amdgcn_s_setprio(1);
    COMPUTE(p, 0, 1);
    __builtin_amdgcn_s_setprio(0);
    __builtin_amdgcn_sched_barrier(0);
    if (kt < 7) WRITEA(pn);                   // compiler waits vmcnt(4): av(kt+1)
    __builtin_amdgcn_sched_barrier(0);
    if (kt < 6) LOADA(kt + 2);                // crosses the barrier below
    __builtin_amdgcn_sched_barrier(0);
    __builtin_amdgcn_s_setprio(1);
    COMPUTE(p, 2, 3);
    __builtin_amdgcn_s_setprio(0);
    __builtin_amdgcn_sched_barrier(0);
    if (kt < 6) {
      asm volatile("s_waitcnt vmcnt(8) lgkmcnt(0)" ::: "memory");  // B(kt+1) done
      __builtin_amdgcn_sched_barrier(0);
      __builtin_amdgcn_s_barrier();
      __builtin_amdgcn_sched_barrier(0);
    } else if (kt == 6) {
      asm volatile("s_waitcnt vmcnt(0) lgkmcnt(0)" ::: "memory");  // B(7) done
      __builtin_amdgcn_sched_barrier(0);
      __builtin_amdgcn_s_barrier();
      __builtin_amdgcn_sched_barrier(0);
    }
  }

  // ---- epilogue: tanh + Wo col-sum, transpose-reduce (r9-verified), atomics ----
#pragma unroll
  for (int rp = 0; rp < 2; ++rp) {
    float v[32];
#pragma unroll
    for (int mm = 0; mm < 2; ++mm)
#pragma unroll
      for (int r = 0; r < 16; ++r)
        v[mm * 16 + r] = w0 * fast_tanh(acc[rp * 2 + mm][0][r] + q0)
                       + w1 * fast_tanh(acc[rp * 2 + mm][1][r] + q1);
#pragma unroll
    for (int sdist = 16; sdist >= 1; sdist >>= 1) {
#pragma unroll
      for (int i = 0; i < sdist; ++i) {
        float a = v[i], c = v[i + sdist];
        float keep = (lo & sdist) ? c : a;
        float send = (lo & sdist) ? a : c;
        v[i] = keep + __shfl_xor(send, sdist, 64);
      }
    }
    int rr = lo & 15;
    int m = rp * 2 + (lo >> 4);
    int grow = mtile * 256 + wm * 128 + m * 32 + (rr & 3) + 8 * (rr >> 2) + 4 * hi;
    atomicAdd(&logit[grow], v[0]);
  }
#undef LOADA
#undef WRITEA
#undef GLDSB
#undef COMPUTE
}

// ---------------- weights: mask*exp(logit+bo), normalize over L ----------------
__global__ __launch_bounds__(256) void k_weights(const float* __restrict__ mask,
                                                 const float* __restrict__ bo,
                                                 const float* __restrict__ logit,
                                                 float* __restrict__ wout) {
  __shared__ float red[4];
  int b = blockIdx.x, t = threadIdx.x;
  float bov = bo[0];
  float w[8];
  float s = 0.f;
#pragma unroll
  for (int i = 0; i < 8; ++i) {
    int l = t + 256 * i;
    float e = mask[b * LL + l] * __expf(logit[b * LL + l] + bov);
    w[i] = e; s += e;
  }
#pragma unroll
  for (int m = 32; m >= 1; m >>= 1) s += __shfl_xor(s, m, 64);
  int wave = t >> 6, lane = t & 63;
  if (lane == 0) red[wave] = s;
  __syncthreads();
  float inv = 1.0f / (red[0] + red[1] + red[2] + red[3] + 1e-5f);
#pragma unroll
  for (int i = 0; i < 8; ++i) wout[b * LL + t + 256 * i] = w[i] * inv;
}

// ---------------- output[b][c] = sum_l weights[b][l] * ctx[b][l][c] (ctx in L3) ----
__global__ __launch_bounds__(256) void k_output_f32(const float* __restrict__ ctx,
                                                    const float* __restrict__ weights,
                                                    float* __restrict__ out) {
  __shared__ float wl[128];
  int bid = blockIdx.x;            // 512 = 32 b * 16 chunks
  int b = bid >> 4, chunk = bid & 15;
  int t = threadIdx.x;
  int l0 = chunk * 128;
  if (t < 128) wl[t] = weights[b * LL + l0 + t];
  __syncthreads();
  const float2* c2 = (const float2*)(ctx + ((size_t)(b * LL + l0)) * CH) + t;
  float ax = 0.f, ay = 0.f;
#pragma unroll 4
  for (int l = 0; l < 128; ++l) {
    float wv = wl[l];
    float2 v = c2[(size_t)l * (CH / 2)];
    ax += wv * v.x; ay += wv * v.y;
  }
  atomicAdd(&out[b * CH + 2 * t], ax);
  atomicAdd(&out[b * CH + 2 * t + 1], ay);
}

extern "C" void kernel_launch(void* const* d_in, const int* in_sizes, int n_in,
                              void* d_out, int out_size, void* d_ws, size_t ws_size,
                              hipStream_t stream) {
  const float* query = (const float*)d_in[0];
  const float* ctx   = (const float*)d_in[1];
  const float* mask  = (const float*)d_in[2];
  const float* Wq    = (const float*)d_in[3];
  const float* Wc    = (const float*)d_in[4];
  const float* bc    = (const float*)d_in[5];
  const float* Wo    = (const float*)d_in[6];
  const float* bo    = (const float*)d_in[7];
  float* out = (float*)d_out;

  uint4* wcbp  = (uint4*)d_ws;                                    // 1 MB packed bf16 Wc
  float* resqc = (float*)((char*)d_ws + (1 << 20));               // 128 KB
  float* logit = (float*)((char*)d_ws + (1 << 20) + (1 << 17));   // 256 KB
  float* wout = out + NB * CH;                                    // final weights slot

  k_prep<<<401, 256, 0, stream>>>(Wc, wcbp, query, Wq, bc, resqc, logit, out);
  k_logits_t<<<1024, 512, 0, stream>>>(ctx, wcbp, resqc, Wo, logit);
  k_weights<<<32, 256, 0, stream>>>(mask, bo, logit, wout);
  k_output_f32<<<512, 256, 0, stream>>>(ctx, wout, out);
}

// Round 16
// 127.601 us; speedup vs baseline: 1.0247x; 1.0230x over previous
//
#include <hip/hip_runtime.h>

#define NB 32
#define LL 2048
#define CH 512
#define BQ 512
#define HH 1024

typedef __attribute__((ext_vector_type(8))) short bf16x8;
typedef __attribute__((ext_vector_type(16))) float f32x16;

__device__ __forceinline__ unsigned int cvt_pk_bf16(float a, float b) {
  unsigned int r;
  asm("v_cvt_pk_bf16_f32 %0, %1, %2" : "=v"(r) : "v"(a), "v"(b));
  return r;   // lo16 = bf16(a), hi16 = bf16(b)
}

__device__ __forceinline__ float fast_tanh(float x) {
  float e = __builtin_amdgcn_exp2f(x * 2.885390081777927f);
  return 1.0f - 2.0f * __builtin_amdgcn_rcpf(e + 1.0f);
}

// ================ fused small prep ================
// [0,256)   : pack Wc -> wcbp (B-frag order, 65536 uint4)
// [256,384) : res_qc = query@Wq^T + bc (32768)
// [384,400) : zero logit (65536 f32)
// 400       : zero out (16384 f32)
__global__ __launch_bounds__(256) void k_prep(const float* __restrict__ Wc,
                                              uint4* __restrict__ wcbp,
                                              const float* __restrict__ query,
                                              const float* __restrict__ Wq,
                                              const float* __restrict__ bc,
                                              float* __restrict__ resqc,
                                              float* __restrict__ logit,
                                              float* __restrict__ out) {
  int bid = blockIdx.x, t = threadIdx.x;
  if (bid < 256) {
    int gid = bid * 256 + t;   // 65536 = 32 cg * 32 ks * 64 lanes
    int lane = gid & 63, ks = (gid >> 6) & 31, cg = gid >> 11;
    int lo = lane & 31, hi = lane >> 5;
    const float4* s = (const float4*)(Wc + (size_t)(cg * 32 + lo) * CH + hi * 8 + ks * 16);
    float4 v0 = s[0], v1 = s[1];
    uint4 p;
    p.x = cvt_pk_bf16(v0.x, v0.y);
    p.y = cvt_pk_bf16(v0.z, v0.w);
    p.z = cvt_pk_bf16(v1.x, v1.y);
    p.w = cvt_pk_bf16(v1.z, v1.w);
    wcbp[gid] = p;
  } else if (bid < 384) {
    int gid = (bid - 256) * 256 + t;   // 32768
    int b = gid >> 10, h = gid & 1023;
    const float4* q4 = (const float4*)(query + (size_t)b * BQ);
    const float4* w4 = (const float4*)(Wq + (size_t)h * BQ);
    float acc = 0.f;
#pragma unroll 4
    for (int i = 0; i < BQ / 4; ++i) {
      float4 a = q4[i], w = w4[i];
      acc += a.x * w.x + a.y * w.y + a.z * w.z + a.w * w.w;
    }
    resqc[gid] = acc + bc[h];
  } else if (bid < 400) {
    float4* p = (float4*)logit + (bid - 384) * 1024 + t;
#pragma unroll
    for (int i = 0; i < 4; ++i) p[i * 256] = (float4){0, 0, 0, 0};
  } else {
    float4* p = (float4*)out + t;
#pragma unroll
    for (int i = 0; i < 16; ++i) p[i * 256] = (float4){0, 0, 0, 0};
  }
}

// ---------------- main: one 64-row tile per block, A in LDS, 2 blocks/CU ----
// 2048 blocks = 32 b x 32 rowtiles x 2 N-halves; 512 thr (8 waves). Wave =
// 64r x 64c, acc[2][2]=64 AGPR. A: [64][520] bf16 LDS. B: packed wcbp via
// saddr loads, DIRECT bf16x8 (no uint4/memcpy round-trip). kg-loop unroll 2
// so next group's B loads issue under current MFMAs.
__global__ __launch_bounds__(512, 4) void k_logits_f(const float* __restrict__ ctx,
                                                     const uint4* __restrict__ bpk,
                                                     const float* __restrict__ resqc,
                                                     const float* __restrict__ Wo,
                                                     float* __restrict__ logit) {
  __shared__ unsigned short A[64 * 520];   // 66560 B

  const int t = threadIdx.x;
  const int bid = blockIdx.x;
  // XCD pair-swizzle: both N-halves of one A-tile land adjacent on one XCD
  const int swz = (bid & 7) * 256 + (bid >> 3);
  const int lt = swz >> 1, nh = swz & 1;
  const int b = lt >> 5, row0 = (lt & 31) << 6;

  // stage A tile: 64 rows x 512 f32 -> bf16 LDS. Strength-reduced: per-thread
  // col c4 fixed, row walks by +4 each iteration.
  {
    const int r0 = t >> 7, c4 = t & 127;
    const float4* src = (const float4*)(ctx + ((size_t)(b * LL + row0)) * CH) + (size_t)r0 * 128 + c4;
    unsigned short* dst = A + r0 * 520 + c4 * 4;
#pragma unroll
    for (int i = 0; i < 16; ++i) {
      float4 v = src[(size_t)i * 512];     // +4 rows = 4*128 float4
      uint2 w;
      w.x = cvt_pk_bf16(v.x, v.y);
      w.y = cvt_pk_bf16(v.z, v.w);
      *(uint2*)(dst + i * (4 * 520)) = w;
    }
  }
  __syncthreads();

  const int wv = t >> 6, lane = t & 63;
  const int lo = lane & 31, hi = lane >> 5;

  // wave-uniform B base -> saddr loads; fixed per-lane voffset
  const int wvu = __builtin_amdgcn_readfirstlane(wv);
  const char* b0 = (const char*)(bpk + (size_t)((nh * 16 + wvu * 2) * 32) * 64);
  const char* b1 = b0 + 32768;
  const unsigned vo = lane * 16;

  const char* a0 = (const char*)A + lo * 1040 + hi * 16;   // rows lo / lo+32

  f32x16 acc[2][2];
#pragma unroll
  for (int m = 0; m < 2; ++m)
#pragma unroll
    for (int n = 0; n < 2; ++n) acc[m][n] = (f32x16){0,0,0,0,0,0,0,0,0,0,0,0,0,0,0,0};

#pragma unroll 2
  for (int kg = 0; kg < 8; ++kg) {   // 8 groups x 4 ks
#pragma unroll
    for (int j = 0; j < 4; ++j) {
      bf16x8 fb0 = *(const bf16x8*)(b0 + vo + j * 1024);   // direct: no memcpy
      bf16x8 fb1 = *(const bf16x8*)(b1 + vo + j * 1024);
      bf16x8 fa0 = *(const bf16x8*)(a0 + kg * 128 + j * 32);
      bf16x8 fa1 = *(const bf16x8*)(a0 + 33280 + kg * 128 + j * 32);
      acc[0][0] = __builtin_amdgcn_mfma_f32_32x32x16_bf16(fa0, fb0, acc[0][0], 0, 0, 0);
      acc[0][1] = __builtin_amdgcn_mfma_f32_32x32x16_bf16(fa0, fb1, acc[0][1], 0, 0, 0);
      acc[1][0] = __builtin_amdgcn_mfma_f32_32x32x16_bf16(fa1, fb0, acc[1][0], 0, 0, 0);
      acc[1][1] = __builtin_amdgcn_mfma_f32_32x32x16_bf16(fa1, fb1, acc[1][1], 0, 0, 0);
    }
    b0 += 4096; b1 += 4096;   // uniform SALU bumps
  }

  // epilogue: tanh + Wo-weighted col-sum -> transpose-reduce -> global atomics
  const int c0 = nh * 512 + wv * 64;
  float q0 = resqc[b * HH + c0 + lo], q1 = resqc[b * HH + c0 + 32 + lo];
  float w0 = Wo[c0 + lo],             w1 = Wo[c0 + 32 + lo];
  float v[32];
#pragma unroll
  for (int m = 0; m < 2; ++m)
#pragma unroll
    for (int r = 0; r < 16; ++r)
      v[m * 16 + r] = w0 * fast_tanh(acc[m][0][r] + q0)
                    + w1 * fast_tanh(acc[m][1][r] + q1);
  // transpose-reduce over 32 col-lanes: lane lo ends with the full sum of value lo
#pragma unroll
  for (int sdist = 16; sdist >= 1; sdist >>= 1) {
#pragma unroll
    for (int i = 0; i < sdist; ++i) {
      float a = v[i], c = v[i + sdist];
      float keep = (lo & sdist) ? c : a;
      float send = (lo & sdist) ? a : c;
      v[i] = keep + __shfl_xor(send, sdist, 64);
    }
  }
  int rr = lo & 15;
  int row_local = (lo >> 4) * 32 + (rr & 3) + 8 * (rr >> 2) + 4 * hi;  // C/D row map
  atomicAdd(&logit[(size_t)b * LL + row0 + row_local], v[0]);
}

// ---------------- weights: mask*exp(logit+bo), normalize over L ----------------
__global__ __launch_bounds__(256) void k_weights(const float* __restrict__ mask,
                                                 const float* __restrict__ bo,
                                                 const float* __restrict__ logit,
                                                 float* __restrict__ wout) {
  __shared__ float red[4];
  int b = blockIdx.x, t = threadIdx.x;
  float bov = bo[0];
  float w[8];
  float s = 0.f;
#pragma unroll
  for (int i = 0; i < 8; ++i) {
    int l = t + 256 * i;
    float e = mask[b * LL + l] * __expf(logit[b * LL + l] + bov);
    w[i] = e; s += e;
  }
#pragma unroll
  for (int m = 32; m >= 1; m >>= 1) s += __shfl_xor(s, m, 64);
  int wave = t >> 6, lane = t & 63;
  if (lane == 0) red[wave] = s;
  __syncthreads();
  float inv = 1.0f / (red[0] + red[1] + red[2] + red[3] + 1e-5f);
#pragma unroll
  for (int i = 0; i < 8; ++i) wout[b * LL + t + 256 * i] = w[i] * inv;
}

// ---------------- output[b][c] = sum_l weights[b][l] * ctx[b][l][c] (ctx in L3) ----
__global__ __launch_bounds__(256) void k_output_f32(const float* __restrict__ ctx,
                                                    const float* __restrict__ weights,
                                                    float* __restrict__ out) {
  __shared__ float wl[128];
  int bid = blockIdx.x;            // 512 = 32 b * 16 chunks
  int b = bid >> 4, chunk = bid & 15;
  int t = threadIdx.x;
  int l0 = chunk * 128;
  if (t < 128) wl[t] = weights[b * LL + l0 + t];
  __syncthreads();
  const float2* c2 = (const float2*)(ctx + ((size_t)(b * LL + l0)) * CH) + t;
  float ax = 0.f, ay = 0.f;
#pragma unroll 4
  for (int l = 0; l < 128; ++l) {
    float wv = wl[l];
    float2 v = c2[(size_t)l * (CH / 2)];
    ax += wv * v.x; ay += wv * v.y;
  }
  atomicAdd(&out[b * CH + 2 * t], ax);
  atomicAdd(&out[b * CH + 2 * t + 1], ay);
}

extern "C" void kernel_launch(void* const* d_in, const int* in_sizes, int n_in,
                              void* d_out, int out_size, void* d_ws, size_t ws_size,
                              hipStream_t stream) {
  const float* query = (const float*)d_in[0];
  const float* ctx   = (const float*)d_in[1];
  const float* mask  = (const float*)d_in[2];
  const float* Wq    = (const float*)d_in[3];
  const float* Wc    = (const float*)d_in[4];
  const float* bc    = (const float*)d_in[5];
  const float* Wo    = (const float*)d_in[6];
  const float* bo    = (const float*)d_in[7];
  float* out = (float*)d_out;

  uint4* wcbp  = (uint4*)d_ws;                                    // 1 MB packed bf16 Wc
  float* resqc = (float*)((char*)d_ws + (1 << 20));               // 128 KB
  float* logit = (float*)((char*)d_ws + (1 << 20) + (1 << 17));   // 256 KB
  float* wout = out + NB * CH;                                    // final weights slot

  k_prep<<<401, 256, 0, stream>>>(Wc, wcbp, query, Wq, bc, resqc, logit, out);
  k_logits_f<<<2048, 512, 0, stream>>>(ctx, wcbp, resqc, Wo, logit);
  k_weights<<<32, 256, 0, stream>>>(mask, bo, logit, wout);
  k_output_f32<<<512, 256, 0, stream>>>(ctx, wout, out);
}